// Round 1
// baseline (115.369 us; speedup 1.0000x reference)
//
#include <hip/hip_runtime.h>

typedef _Float16 half4_t __attribute__((ext_vector_type(4)));
typedef _Float16 half8_t __attribute__((ext_vector_type(8)));
typedef float    f32x4   __attribute__((ext_vector_type(4)));

#define BS   128
#define DH   64
#define PROW 132   // padded LDS row length (f16 elems): 264 B, 8B-aligned rows

__device__ __forceinline__ half8_t load8_f16(const float* p, float scale) {
  float4 a = *(const float4*)(p);
  float4 b = *(const float4*)(p + 4);
  half8_t h;
  h[0] = (_Float16)(a.x * scale); h[1] = (_Float16)(a.y * scale);
  h[2] = (_Float16)(a.z * scale); h[3] = (_Float16)(a.w * scale);
  h[4] = (_Float16)(b.x * scale); h[5] = (_Float16)(b.y * scale);
  h[6] = (_Float16)(b.z * scale); h[7] = (_Float16)(b.w * scale);
  return h;
}

__device__ __forceinline__ half8_t lds_read8(const _Float16* p) {
  half4_t lo = *(const half4_t*)(p);
  half4_t hi = *(const half4_t*)(p + 4);
  return __builtin_shufflevector(lo, hi, 0, 1, 2, 3, 4, 5, 6, 7);
}

__global__ __launch_bounds__(256, 1) void ball_attn_kernel(
    const float* __restrict__ Q, const float* __restrict__ Kk,
    const float* __restrict__ V, float* __restrict__ O) {
  // V^T (all waves share) + per-wave P scratch
  __shared__ __align__(16) _Float16 VT[DH][PROW];      // [d][key]
  __shared__ __align__(16) _Float16 Pl[4][32][PROW];   // [wave][qrow][key]

  const int tid  = threadIdx.x;
  const int w    = tid >> 6;   // wave 0..3, owns q rows [32w, 32w+32)
  const int lane = tid & 63;
  const int c    = lane & 15;  // MFMA col/row-within-tile index
  const int g    = lane >> 4;  // MFMA 16-lane group 0..3

  const size_t base = (size_t)blockIdx.x * (BS * DH);  // ball is contiguous
  const float* Qb = Q  + base;
  const float* Kb = Kk + base;
  const float* Vb = V  + base;
  float*       Ob = O  + base;

  // ---- stage V^T (f32 -> f16) into LDS; coalesced float4 global reads ----
  {
    const int kq = tid >> 4;        // 0..15
    const int d0 = (tid & 15) * 4;  // 0..60
#pragma unroll
    for (int it = 0; it < 8; ++it) {
      const int key = it * 16 + kq;
      const float4 v4 = *(const float4*)(Vb + key * DH + d0);
      VT[d0 + 0][key] = (_Float16)v4.x;
      VT[d0 + 1][key] = (_Float16)v4.y;
      VT[d0 + 2][key] = (_Float16)v4.z;
      VT[d0 + 3][key] = (_Float16)v4.w;
    }
  }

  // ---- Q fragments (scale 1/sqrt(64)=0.125 folded in, exact) ----
  half8_t aq[2][2];
#pragma unroll
  for (int m = 0; m < 2; ++m)
#pragma unroll
    for (int ks = 0; ks < 2; ++ks)
      aq[m][ks] = load8_f16(Qb + (w * 32 + m * 16 + c) * DH + ks * 32 + g * 8, 0.125f);

  // ---- S = Q K^T  (both operands row-major fragments -> D = A * B^T) ----
  f32x4 acc[2][8];
#pragma unroll
  for (int m = 0; m < 2; ++m)
#pragma unroll
    for (int kt = 0; kt < 8; ++kt)
      acc[m][kt] = (f32x4){0.f, 0.f, 0.f, 0.f};

#pragma unroll
  for (int kt = 0; kt < 8; ++kt) {
#pragma unroll
    for (int ks = 0; ks < 2; ++ks) {
      const half8_t bk = load8_f16(Kb + (kt * 16 + c) * DH + ks * 32 + g * 8, 1.0f);
      acc[0][kt] = __builtin_amdgcn_mfma_f32_16x16x32_f16(aq[0][ks], bk, acc[0][kt], 0, 0, 0);
      acc[1][kt] = __builtin_amdgcn_mfma_f32_16x16x32_f16(aq[1][ks], bk, acc[1][kt], 0, 0, 0);
    }
  }

  // ---- softmax; lane holds rows (m*16 + 4g + r), cols kt*16 + c ----
  float rsum_inv[2][4];
#pragma unroll
  for (int m = 0; m < 2; ++m) {
    float mx[4], sm[4];
#pragma unroll
    for (int r = 0; r < 4; ++r) {
      mx[r] = acc[m][0][r];
#pragma unroll
      for (int kt = 1; kt < 8; ++kt) mx[r] = fmaxf(mx[r], acc[m][kt][r]);
    }
#pragma unroll
    for (int r = 0; r < 4; ++r) {   // reduce over the 16 col-lanes (bits 0..3)
      mx[r] = fmaxf(mx[r], __shfl_xor(mx[r], 1));
      mx[r] = fmaxf(mx[r], __shfl_xor(mx[r], 2));
      mx[r] = fmaxf(mx[r], __shfl_xor(mx[r], 4));
      mx[r] = fmaxf(mx[r], __shfl_xor(mx[r], 8));
      sm[r] = 0.f;
    }
#pragma unroll
    for (int kt = 0; kt < 8; ++kt)
#pragma unroll
      for (int r = 0; r < 4; ++r) {
        const float p = __expf(acc[m][kt][r] - mx[r]);
        acc[m][kt][r] = p;
        sm[r] += p;
      }
#pragma unroll
    for (int r = 0; r < 4; ++r) {
      sm[r] += __shfl_xor(sm[r], 1);
      sm[r] += __shfl_xor(sm[r], 2);
      sm[r] += __shfl_xor(sm[r], 4);
      sm[r] += __shfl_xor(sm[r], 8);
      rsum_inv[m][r] = 1.0f / sm[r];   // sum >= 1 (max term is 1), no div0
    }
    // write P (f16) to per-wave LDS; same-wave LDS is ordered -> no barrier
#pragma unroll
    for (int kt = 0; kt < 8; ++kt)
#pragma unroll
      for (int r = 0; r < 4; ++r)
        Pl[w][m * 16 + 4 * g + r][kt * 16 + c] = (_Float16)acc[m][kt][r];
  }

  __syncthreads();   // V^T visible to all waves

  // ---- O = P V : A = P rows (key-contig), B = V^T rows (key-contig) ----
  f32x4 o[2][4];
#pragma unroll
  for (int m = 0; m < 2; ++m)
#pragma unroll
    for (int t = 0; t < 4; ++t) o[m][t] = (f32x4){0.f, 0.f, 0.f, 0.f};

#pragma unroll
  for (int ks = 0; ks < 4; ++ks) {
    half8_t pf[2];
#pragma unroll
    for (int m = 0; m < 2; ++m)
      pf[m] = lds_read8(&Pl[w][m * 16 + c][ks * 32 + g * 8]);
#pragma unroll
    for (int t = 0; t < 4; ++t) {
      const half8_t vf = lds_read8(&VT[t * 16 + c][ks * 32 + g * 8]);
      o[0][t] = __builtin_amdgcn_mfma_f32_16x16x32_f16(pf[0], vf, o[0][t], 0, 0, 0);
      o[1][t] = __builtin_amdgcn_mfma_f32_16x16x32_f16(pf[1], vf, o[1][t], 0, 0, 0);
    }
  }

  // ---- scale by 1/rowsum and store (row mapping matches softmax) ----
#pragma unroll
  for (int m = 0; m < 2; ++m)
#pragma unroll
    for (int t = 0; t < 4; ++t)
#pragma unroll
      for (int r = 0; r < 4; ++r)
        Ob[(w * 32 + m * 16 + 4 * g + r) * DH + t * 16 + c] = o[m][t][r] * rsum_inv[m][r];
}

extern "C" void kernel_launch(void* const* d_in, const int* in_sizes, int n_in,
                              void* d_out, int out_size, void* d_ws, size_t ws_size,
                              hipStream_t stream) {
  const float* q = (const float*)d_in[0];
  const float* k = (const float*)d_in[1];
  const float* v = (const float*)d_in[2];
  float* out = (float*)d_out;
  const int nballs = in_sizes[0] / (BS * DH);  // 4*16*8192*64 / 8192 = 4096
  ball_attn_kernel<<<dim3(nballs), dim3(256), 0, stream>>>(q, k, v, out);
}